// Round 3
// 344.590 us; speedup vs baseline: 1.0829x; 1.0829x over previous
//
#include <hip/hip_runtime.h>
#include <hip/hip_fp16.h>

// ---------------------------------------------------------------------------
// GCNEncoder: 3x GCNConv(128->128) + ReLU(2x) + global mean pool (64 graphs)
//   - CSR build, ZERO global atomics (two-level counting sort).
//   - dinv[src] folded into GEMM epilogue (xw' = dinv*xw); csr = 4B
//     {src:u16, fp16(ew*dinv_dst)} finalized inside bucket_k.
//   - agg_k at the L2-miss/fabric service floor (FETCH ~1.4x compulsory);
//     R12: inner loop unrolled 8-deep to test queue-depth vs service bound.
//   - R12: scan_small256 eliminated (scanb at 2048/blk -> 38 sums; consumers
//     scan raw blksum in-LDS with one wave). div_k eliminated (graph counts
//     from sorted-batch boundary detection in scanb, inverted in scat blk 0,
//     pool_k pre-scales partial sums). 13 -> 11 dispatches.
//   - R13 FIX: in_sizes/out_size are in ELEMENTS -> ngraph = out_size/DFEAT
//     (was /(DFEAT*4) = 16, leaving pool_inv[16..63] uninitialized).
//   - R14: identical resubmit (R13 bench was an infra failure, no data).
// ---------------------------------------------------------------------------

#define DFEAT 128
#define BLK_E 4096   // edges per sort block
#define NPART 8

typedef _Float16 half8 __attribute__((ext_vector_type(8)));
typedef float floatx4 __attribute__((ext_vector_type(4)));

__device__ __forceinline__ int wave_incl_scan(int v) {
    int incl = v;
    #pragma unroll
    for (int off = 1; off < 64; off <<= 1) {
        int u = __shfl_up(incl, (unsigned)off, 64);
        if ((int)(threadIdx.x & 63) >= off) incl += u;
    }
    return incl;
}

__device__ __forceinline__ void wconv_elem(int idx, const float* __restrict__ W0,
                                           const float* __restrict__ W1,
                                           const float* __restrict__ W2,
                                           _Float16* __restrict__ Wsw) {
    if (idx >= 3 * 128 * 128) return;
    int w = idx >> 14;
    int r = idx & 16383;
    int k = r >> 7, nn = r & 127;
    const float* W = (w == 0) ? W0 : (w == 1) ? W1 : W2;
    float v = W[k * 128 + nn];
    _Float16 hi = (_Float16)v;
    _Float16 lo = (_Float16)((v - (float)hi) * 1024.0f);
    int kk = k >> 5, quad = (k >> 3) & 3, j = k & 7;
    int t = nn >> 4, L = quad * 16 + (nn & 15);
    int off = ((kk * 8 + t) * 64 + L) * 8 + j;
    Wsw[(size_t)(w * 2 + 0) * 16384 + off] = hi;
    Wsw[(size_t)(w * 2 + 1) * 16384 + off] = lo;
}

// K1: per-block histogram over coarse buckets (dst >> 8), bin-major output.
// Fused side work: blocks 0..47 convert/swizzle W (1024 elems each);
// blocks 0..7 zero `out` (1024 floats each).
__global__ __launch_bounds__(256) void hist_k(const int* __restrict__ dst,
                                              int* __restrict__ hist,
                                              const float* __restrict__ W0,
                                              const float* __restrict__ W1,
                                              const float* __restrict__ W2,
                                              _Float16* __restrict__ Wsw,
                                              float* __restrict__ out,
                                              int E, int nblk, int nbuck) {
    __shared__ int h[256];
    int tid = threadIdx.x, b = blockIdx.x;
    h[tid] = 0;
    // fused side work (no barrier interaction; independent outputs)
    if (b < 48) {
        #pragma unroll
        for (int k = 0; k < 4; k++)
            wconv_elem(b * 1024 + k * 256 + tid, W0, W1, W2, Wsw);
    }
    if (b < 8) {
        floatx4 z = {0.f, 0.f, 0.f, 0.f};
        ((floatx4*)out)[b * 256 + tid] = z;   // 8 blocks x 256 x 4 = 8192
    }
    __syncthreads();
    int base = b * BLK_E;
    int nE = min(BLK_E, E - base);
    for (int i = tid; i < nE; i += 256) atomicAdd(&h[dst[base + i] >> 8], 1);
    __syncthreads();
    if (tid < nbuck) hist[tid * nblk + b] = h[tid];
}

// Block-local exclusive scan, 2048 elems/block (8/thread), in-place;
// blksum = RAW per-block totals (consumers scan the <=64 of them in-LDS).
// Fused: graph end-index detection on sorted `batch` for mean-pool counts.
__global__ __launch_bounds__(256) void scanb_k(int* __restrict__ arr,
                                               int* __restrict__ blksum,
                                               const int* __restrict__ batch,
                                               int* __restrict__ gend,
                                               int n_val, int n_scan,
                                               int N, int ngraph) {
    int tid = threadIdx.x;
    int base = blockIdx.x * 2048 + tid * 8;
    int v[8], tsum = 0;
    #pragma unroll
    for (int j = 0; j < 8; j++) {
        v[j] = (base + j < n_val) ? arr[base + j] : 0;
        tsum += v[j];
    }
    int incl = wave_incl_scan(tsum);
    __shared__ int wtot[4];
    if ((tid & 63) == 63) wtot[tid >> 6] = incl;
    __syncthreads();
    int woff = 0;
    for (int w = 0; w < (tid >> 6); w++) woff += wtot[w];
    int run = woff + incl - tsum;
    #pragma unroll
    for (int j = 0; j < 8; j++) {
        if (base + j < n_scan) arr[base + j] = run;
        run += v[j];
    }
    if (tid == 255) blksum[blockIdx.x] = woff + incl;
    // fused: per-graph end indices (batch is sorted; handles empty graphs)
    int stride = gridDim.x * 256;
    for (int i = blockIdx.x * 256 + tid; i < N; i += stride) {
        int b0 = batch[i];
        int b1 = (i + 1 < N) ? batch[i + 1] : ngraph;
        if (i == 0) for (int g = 0; g < b0; g++) gend[g] = 0;
        if (b0 != b1) for (int g = b0; g < b1; g++) gend[g] = i + 1;
    }
}

// K3: scatter edges into bucket-grouped array, coalesced via LDS sort.
// rec = {src | dstlow<<16, ew_bits}. Requires N <= 65536. 512 threads.
// Fused: wave 4 scans raw blksum in-LDS; block 0 inverts pool counts.
__global__ __launch_bounds__(512) void scat_k(const int* __restrict__ src,
                                              const int* __restrict__ dst,
                                              const float* __restrict__ ew,
                                              const int* __restrict__ offs,
                                              const int* __restrict__ blksum,
                                              const int* __restrict__ gend,
                                              float* __restrict__ pool_inv,
                                              uint2* __restrict__ rec,
                                              int E, int nblk, int nbuck,
                                              int nsb, int ngraph) {
    __shared__ int lcur[256];
    __shared__ int gbase[256];
    __shared__ uint2 srec[BLK_E];
    __shared__ int gpos[BLK_E];
    __shared__ int wtot[4];
    __shared__ int bsc[64];
    int tid = threadIdx.x, b = blockIdx.x;
    if (tid < 256) lcur[tid] = 0;
    if (tid >= 256 && tid < 320) {          // wave 4: exclusive scan of blksum
        int t = tid - 256;
        int v = (t < nsb) ? blksum[t] : 0;
        int incl = wave_incl_scan(v);
        bsc[t] = incl - v;
    }
    if (b == 0 && tid >= 320 && tid < 384) { // block 0: invert graph counts
        int t = tid - 320;
        if (t < ngraph) {
            int c = gend[t] - (t ? gend[t - 1] : 0);
            pool_inv[t] = 1.0f / fmaxf((float)c, 1.0f);
        }
    }
    __syncthreads();
    int base = b * BLK_E;
    int nE = min(BLK_E, E - base);
    for (int i = tid; i < nE; i += 512) atomicAdd(&lcur[dst[base + i] >> 8], 1);
    __syncthreads();
    int v = 0, incl = 0;
    if (tid < 256) { v = lcur[tid]; incl = wave_incl_scan(v); }
    if (tid < 256 && (tid & 63) == 63) wtot[tid >> 6] = incl;
    __syncthreads();
    if (tid < 256) {
        int woff = 0;
        for (int w = 0; w < (tid >> 6); w++) woff += wtot[w];
        int excl = woff + incl - v;
        lcur[tid] = excl;
        int oidx = tid * nblk + b;
        gbase[tid] = (tid < nbuck) ? (offs[oidx] + bsc[oidx >> 11] - excl) : 0;
    }
    __syncthreads();
    for (int i = tid; i < nE; i += 512) {
        int e = base + i;
        int d = dst[e];
        int bin = d >> 8;
        int slot = atomicAdd(&lcur[bin], 1);
        uint2 r;
        r.x = (unsigned)src[e] | ((unsigned)(d & 255) << 16);
        r.y = __float_as_uint(ew[e]);
        srec[slot] = r;
        gpos[slot] = gbase[bin] + slot;
    }
    __syncthreads();
    for (int i = tid; i < nE; i += 512) rec[gpos[i]] = srec[i];
}

// K4: one block per 256-node bucket. Per-(node, src>>13) counts + fixed-point
// deg in LDS, 2048-wide scan -> rp8 segment offsets + dinv, then place FINAL
// 4B CSR entries {src:u16, fp16(ew*dinv_dst)} grouped by src partition.
__global__ __launch_bounds__(1024) void bucket_k(const uint2* __restrict__ rec,
                                                 const int* __restrict__ offs,
                                                 const int* __restrict__ blksum,
                                                 float* __restrict__ dinv,
                                                 int* __restrict__ rp8,
                                                 unsigned* __restrict__ csr,
                                                 int N, int nblk, int nsb) {
    __shared__ int cnt[2048];       // key = dl*8 + (src>>13)
    __shared__ unsigned degfx[256];
    __shared__ int cur[2048];
    __shared__ int wtot[16];
    __shared__ int bsc[64];
    int tid = threadIdx.x, bin = blockIdx.x;
    cnt[tid] = 0; cnt[tid + 1024] = 0;
    if (tid < 256) degfx[tid] = 0;
    if (tid >= 256 && tid < 320) {          // exclusive scan of raw blksum
        int t = tid - 256;
        int v = (t < nsb) ? blksum[t] : 0;
        int incl = wave_incl_scan(v);
        bsc[t] = incl - v;
    }
    __syncthreads();
    int idx0 = bin * nblk, idx1 = (bin + 1) * nblk;
    int start = offs[idx0] + bsc[idx0 >> 11];
    int endp  = offs[idx1] + bsc[idx1 >> 11];  // sentinel -> E for last bin
    for (int i = start + tid; i < endp; i += 1024) {
        uint2 r = rec[i];
        int dl = (r.x >> 16) & 255;
        int part = (r.x & 0xffff) >> 13;
        atomicAdd(&cnt[dl * NPART + part], 1);
        atomicAdd(&degfx[dl], (unsigned)(__uint_as_float(r.y) * 1048576.0f + 0.5f));
    }
    __syncthreads();
    int v0 = cnt[tid * 2], v1 = cnt[tid * 2 + 1];
    int tsum = v0 + v1;
    int incl = wave_incl_scan(tsum);
    if ((tid & 63) == 63) wtot[tid >> 6] = incl;
    __syncthreads();
    int woff = 0;
    for (int w = 0; w < (tid >> 6); w++) woff += wtot[w];
    int texcl = woff + incl - tsum;
    cur[tid * 2] = texcl;
    cur[tid * 2 + 1] = texcl + v0;
    // nodes >= N in the tail bucket have zero counts -> their rp8 slots get
    // the bucket end offset, which serves as the sentinel for node N-1.
    rp8[bin * 2048 + tid * 2] = start + texcl;
    rp8[bin * 2048 + tid * 2 + 1] = start + texcl + v0;
    __syncthreads();
    if (tid < 256) {
        int node = bin * 256 + tid;
        if (node < N) {
            float deg = (float)degfx[tid] * (1.0f / 1048576.0f) + 1.0f;
            float di = rsqrtf(deg);
            dinv[node] = di;
            degfx[tid] = __float_as_uint(di);   // stash dinv
        }
    }
    __syncthreads();
    for (int i = start + tid; i < endp; i += 1024) {
        uint2 r = rec[i];
        int dl = (r.x >> 16) & 255;
        int s = r.x & 0xffff;
        int part = s >> 13;
        int p = start + atomicAdd(&cur[dl * NPART + part], 1);
        float di_d = __uint_as_float(degfx[dl]);
        float nm = __uint_as_float(r.y) * di_d;   // ew * dinv_dst (final)
        unsigned h = (unsigned)__half_as_ushort(__float2half_rn(nm));
        csr[p] = (unsigned)s | (h << 16);
    }
}

// MFMA GEMM core (A fp16). Epilogue scales row by dinv[row]:
// C[i] = dinv[i] * (A[i] @ W). Block: 8 waves, 128 rows.
__global__ __launch_bounds__(512) void gemm_mfma(const _Float16* __restrict__ A,
                                                 const _Float16* __restrict__ Wsw,
                                                 const float* __restrict__ dinv,
                                                 _Float16* __restrict__ C, int n) {
    __shared__ _Float16 Bl[2 * 16384];
    {
        const uint4* s = (const uint4*)Wsw;
        uint4* d = (uint4*)Bl;
        for (int i = threadIdx.x; i < 4096; i += 512) d[i] = s[i];
    }
    int wave = threadIdx.x >> 6, lane = threadIdx.x & 63;
    int quad = lane >> 4, mcol = lane & 15;
    int row0 = blockIdx.x * 128 + wave * 16 + mcol;
    half8 af[4] = {};
    if (row0 < n) {
        const half8* Arow = (const half8*)(A + (size_t)row0 * DFEAT);
        af[0] = Arow[0 + quad];
        af[1] = Arow[4 + quad];
        af[2] = Arow[8 + quad];
        af[3] = Arow[12 + quad];
    }
    __syncthreads();
    floatx4 acch[8] = {};
    floatx4 accl[8] = {};
    const half8* Bh = (const half8*)Bl;
    const half8* Blo = (const half8*)(Bl + 16384);
    #pragma unroll
    for (int kk = 0; kk < 4; kk++) {
        #pragma unroll
        for (int t = 0; t < 8; t++) {
            half8 bh = Bh[(kk * 8 + t) * 64 + lane];
            acch[t] = __builtin_amdgcn_mfma_f32_16x16x32_f16(af[kk], bh, acch[t], 0, 0, 0);
            half8 bl = Blo[(kk * 8 + t) * 64 + lane];
            accl[t] = __builtin_amdgcn_mfma_f32_16x16x32_f16(af[kk], bl, accl[t], 0, 0, 0);
        }
    }
    int orow_base = blockIdx.x * 128 + wave * 16 + quad * 4;
    float dv[4];
    #pragma unroll
    for (int r = 0; r < 4; r++)
        dv[r] = (orow_base + r < n) ? dinv[orow_base + r] : 0.f;
    #pragma unroll
    for (int t = 0; t < 8; t++) {
        #pragma unroll
        for (int r = 0; r < 4; r++) {
            int orow = orow_base + r;
            if (orow < n) {
                float v = (acch[t][r] + accl[t][r] * (1.0f / 1024.0f)) * dv[r];
                C[(size_t)orow * DFEAT + t * 16 + mcol] = (_Float16)v;
            }
        }
    }
}

// Same, but reads fp32 A (layer 0: x directly).
__global__ __launch_bounds__(512) void gemm_mfma_f32(const float* __restrict__ A,
                                                     const _Float16* __restrict__ Wsw,
                                                     const float* __restrict__ dinv,
                                                     _Float16* __restrict__ C, int n) {
    __shared__ _Float16 Bl[2 * 16384];
    {
        const uint4* s = (const uint4*)Wsw;
        uint4* d = (uint4*)Bl;
        for (int i = threadIdx.x; i < 4096; i += 512) d[i] = s[i];
    }
    int wave = threadIdx.x >> 6, lane = threadIdx.x & 63;
    int quad = lane >> 4, mcol = lane & 15;
    int row0 = blockIdx.x * 128 + wave * 16 + mcol;
    half8 af[4] = {};
    if (row0 < n) {
        const float4* Arow = (const float4*)(A + (size_t)row0 * DFEAT);
        #pragma unroll
        for (int kk = 0; kk < 4; kk++) {
            float4 f0 = Arow[kk * 8 + quad * 2];
            float4 f1 = Arow[kk * 8 + quad * 2 + 1];
            half8 a;
            a[0] = (_Float16)f0.x; a[1] = (_Float16)f0.y;
            a[2] = (_Float16)f0.z; a[3] = (_Float16)f0.w;
            a[4] = (_Float16)f1.x; a[5] = (_Float16)f1.y;
            a[6] = (_Float16)f1.z; a[7] = (_Float16)f1.w;
            af[kk] = a;
        }
    }
    __syncthreads();
    floatx4 acch[8] = {};
    floatx4 accl[8] = {};
    const half8* Bh = (const half8*)Bl;
    const half8* Blo = (const half8*)(Bl + 16384);
    #pragma unroll
    for (int kk = 0; kk < 4; kk++) {
        #pragma unroll
        for (int t = 0; t < 8; t++) {
            half8 bh = Bh[(kk * 8 + t) * 64 + lane];
            acch[t] = __builtin_amdgcn_mfma_f32_16x16x32_f16(af[kk], bh, acch[t], 0, 0, 0);
            half8 bl = Blo[(kk * 8 + t) * 64 + lane];
            accl[t] = __builtin_amdgcn_mfma_f32_16x16x32_f16(af[kk], bl, accl[t], 0, 0, 0);
        }
    }
    int orow_base = blockIdx.x * 128 + wave * 16 + quad * 4;
    float dv[4];
    #pragma unroll
    for (int r = 0; r < 4; r++)
        dv[r] = (orow_base + r < n) ? dinv[orow_base + r] : 0.f;
    #pragma unroll
    for (int t = 0; t < 8; t++) {
        #pragma unroll
        for (int r = 0; r < 4; r++) {
            int orow = orow_base + r;
            if (orow < n) {
                float v = (acch[t][r] + accl[t][r] * (1.0f / 1024.0f)) * dv[r];
                C[(size_t)orow * DFEAT + t * 16 + mcol] = (_Float16)v;
            }
        }
    }
}

// 4 nodes per 256-thread block (one wave each); lane holds 2 fp16 features.
// R12: 8-deep gather unroll (MLP probe; VGPR ~40, still 8 waves/SIMD).
__global__ __launch_bounds__(256) void agg_k(const __half2* __restrict__ xw2,
                                             const int* __restrict__ rp8,
                                             const unsigned* __restrict__ csr,
                                             const float* __restrict__ dinv,
                                             const float* __restrict__ bias,
                                             __half2* __restrict__ out, int relu, int n) {
    int node = blockIdx.x * 4 + (threadIdx.x >> 6);
    if (node >= n) return;
    int lane = threadIdx.x & 63;
    float di = dinv[node];
    float2 selfv = __half22float2(xw2[(size_t)node * 64 + lane]);
    float ax = di * selfv.x, ay = di * selfv.y;
    int e = rp8[node * NPART], end = rp8[node * NPART + NPART];
    for (; e + 8 <= end; e += 8) {
        unsigned c0 = csr[e + 0], c1 = csr[e + 1];
        unsigned c2 = csr[e + 2], c3 = csr[e + 3];
        unsigned c4 = csr[e + 4], c5 = csr[e + 5];
        unsigned c6 = csr[e + 6], c7 = csr[e + 7];
        float2 v0 = __half22float2(xw2[(size_t)(c0 & 0xffff) * 64 + lane]);
        float2 v1 = __half22float2(xw2[(size_t)(c1 & 0xffff) * 64 + lane]);
        float2 v2 = __half22float2(xw2[(size_t)(c2 & 0xffff) * 64 + lane]);
        float2 v3 = __half22float2(xw2[(size_t)(c3 & 0xffff) * 64 + lane]);
        float2 v4 = __half22float2(xw2[(size_t)(c4 & 0xffff) * 64 + lane]);
        float2 v5 = __half22float2(xw2[(size_t)(c5 & 0xffff) * 64 + lane]);
        float2 v6 = __half22float2(xw2[(size_t)(c6 & 0xffff) * 64 + lane]);
        float2 v7 = __half22float2(xw2[(size_t)(c7 & 0xffff) * 64 + lane]);
        float w0 = __half2float(__ushort_as_half((unsigned short)(c0 >> 16)));
        float w1 = __half2float(__ushort_as_half((unsigned short)(c1 >> 16)));
        float w2 = __half2float(__ushort_as_half((unsigned short)(c2 >> 16)));
        float w3 = __half2float(__ushort_as_half((unsigned short)(c3 >> 16)));
        float w4 = __half2float(__ushort_as_half((unsigned short)(c4 >> 16)));
        float w5 = __half2float(__ushort_as_half((unsigned short)(c5 >> 16)));
        float w6 = __half2float(__ushort_as_half((unsigned short)(c6 >> 16)));
        float w7 = __half2float(__ushort_as_half((unsigned short)(c7 >> 16)));
        ax = fmaf(w0, v0.x, ax); ay = fmaf(w0, v0.y, ay);
        ax = fmaf(w1, v1.x, ax); ay = fmaf(w1, v1.y, ay);
        ax = fmaf(w2, v2.x, ax); ay = fmaf(w2, v2.y, ay);
        ax = fmaf(w3, v3.x, ax); ay = fmaf(w3, v3.y, ay);
        ax = fmaf(w4, v4.x, ax); ay = fmaf(w4, v4.y, ay);
        ax = fmaf(w5, v5.x, ax); ay = fmaf(w5, v5.y, ay);
        ax = fmaf(w6, v6.x, ax); ay = fmaf(w6, v6.y, ay);
        ax = fmaf(w7, v7.x, ax); ay = fmaf(w7, v7.y, ay);
    }
    for (; e + 4 <= end; e += 4) {
        unsigned c0 = csr[e + 0], c1 = csr[e + 1];
        unsigned c2 = csr[e + 2], c3 = csr[e + 3];
        float2 v0 = __half22float2(xw2[(size_t)(c0 & 0xffff) * 64 + lane]);
        float2 v1 = __half22float2(xw2[(size_t)(c1 & 0xffff) * 64 + lane]);
        float2 v2 = __half22float2(xw2[(size_t)(c2 & 0xffff) * 64 + lane]);
        float2 v3 = __half22float2(xw2[(size_t)(c3 & 0xffff) * 64 + lane]);
        float w0 = __half2float(__ushort_as_half((unsigned short)(c0 >> 16)));
        float w1 = __half2float(__ushort_as_half((unsigned short)(c1 >> 16)));
        float w2 = __half2float(__ushort_as_half((unsigned short)(c2 >> 16)));
        float w3 = __half2float(__ushort_as_half((unsigned short)(c3 >> 16)));
        ax = fmaf(w0, v0.x, ax); ay = fmaf(w0, v0.y, ay);
        ax = fmaf(w1, v1.x, ax); ay = fmaf(w1, v1.y, ay);
        ax = fmaf(w2, v2.x, ax); ay = fmaf(w2, v2.y, ay);
        ax = fmaf(w3, v3.x, ax); ay = fmaf(w3, v3.y, ay);
    }
    for (; e < end; e++) {
        unsigned c = csr[e];
        float w = __half2float(__ushort_as_half((unsigned short)(c >> 16)));
        float2 v = __half22float2(xw2[(size_t)(c & 0xffff) * 64 + lane]);
        ax = fmaf(w, v.x, ax); ay = fmaf(w, v.y, ay);
    }
    float2 bv = ((const float2*)bias)[lane];
    ax += bv.x; ay += bv.y;
    if (relu) { ax = fmaxf(ax, 0.f); ay = fmaxf(ay, 0.f); }
    out[(size_t)node * 64 + lane] = __floats2half2_rn(ax, ay);
}

// batch is sorted: chunk of 64 nodes per block, 128 threads (one per feature).
// R12: contributions pre-scaled by 1/cnt (pool_inv) -> no div_k pass.
__global__ __launch_bounds__(128) void pool_k(const __half* __restrict__ h,
                                              const int* __restrict__ batch,
                                              float* __restrict__ out,
                                              const float* __restrict__ pool_inv, int n) {
    int j = threadIdx.x;
    int start = blockIdx.x * 64;
    if (start >= n) return;
    int end = start + 64; if (end > n) end = n;
    int g = batch[start];
    float acc = 0.f;
    for (int i = start; i < end; i++) {
        int bi = batch[i];
        if (bi != g) {
            atomicAdd(&out[g * DFEAT + j], acc * pool_inv[g]);
            acc = 0.f; g = bi;
        }
        acc += __half2float(h[(size_t)i * DFEAT + j]);
    }
    atomicAdd(&out[g * DFEAT + j], acc * pool_inv[g]);
}

extern "C" void kernel_launch(void* const* d_in, const int* in_sizes, int n_in,
                              void* d_out, int out_size, void* d_ws, size_t ws_size,
                              hipStream_t stream) {
    const float* x    = (const float*)d_in[0];
    const int*  eidx  = (const int*)d_in[1];
    const float* ew   = (const float*)d_in[2];
    const int*  batch = (const int*)d_in[3];
    const float* W0 = (const float*)d_in[4];
    const float* b0 = (const float*)d_in[5];
    const float* W1 = (const float*)d_in[6];
    const float* b1 = (const float*)d_in[7];
    const float* W2 = (const float*)d_in[8];
    const float* b2 = (const float*)d_in[9];
    float* out = (float*)d_out;

    const int N = in_sizes[0] / DFEAT;   // 50000 (must be <= 65536)
    const int E = in_sizes[2];           // 1600000
    const int ngraph = out_size / DFEAT; // 64 (sizes are in ELEMENTS)
    const int* src = eidx;
    const int* dst = eidx + E;

    const int nbuck = (N + 255) / 256;           // 196
    const int nblk  = (E + BLK_E - 1) / BLK_E;   // 391
    const int total = nbuck * nblk;
    const int n_scan = total + 1;                // sentinel -> E
    const int nsb = (n_scan + 2047) / 2048;      // 38 (must be <= 64)

    size_t off = 0;
    auto walloc = [&](size_t bytes) -> void* {
        void* p = (char*)d_ws + off;
        off += (bytes + 255) & ~(size_t)255;
        return p;
    };
    float*   dinv    = (float*)  walloc((size_t)N * 4);
    int*     rp8     = (int*)    walloc(((size_t)nbuck * 2048 + 8) * 4);
    int*     offs    = (int*)    walloc((size_t)n_scan * 4);
    int*     blksum  = (int*)    walloc(256 * 4);
    uint2*   rec     = (uint2*)  walloc((size_t)E * 8);
    unsigned* csr    = (unsigned*)walloc((size_t)E * 4);
    _Float16* xwH    = (_Float16*)walloc((size_t)N * DFEAT * 2);
    _Float16* hH     = (_Float16*)walloc((size_t)N * DFEAT * 2);
    _Float16* Wsw    = (_Float16*)walloc((size_t)6 * 16384 * 2);
    float*   pool_inv= (float*)  walloc(64 * 4);
    int*     gend    = (int*)    walloc(64 * 4);

    // ---- CSR build (no global atomics); hist fused with wconv + zeroing ----
    hist_k<<<nblk, 256, 0, stream>>>(dst, offs, W0, W1, W2, Wsw, out,
                                     E, nblk, nbuck);
    scanb_k<<<nsb, 256, 0, stream>>>(offs, blksum, batch, gend, total, n_scan,
                                     N, ngraph);
    scat_k<<<nblk, 512, 0, stream>>>(src, dst, ew, offs, blksum, gend, pool_inv,
                                     rec, E, nblk, nbuck, nsb, ngraph);
    bucket_k<<<nbuck, 1024, 0, stream>>>(rec, offs, blksum, dinv, rp8, csr,
                                         N, nblk, nsb);

    int gG = (N + 127) / 128;
    int gA = (N + 3) / 4;
    // layer 0 (reads fp32 x directly)
    gemm_mfma_f32<<<gG, 512, 0, stream>>>(x, Wsw + (size_t)0 * 32768, dinv, xwH, N);
    agg_k<<<gA, 256, 0, stream>>>((const __half2*)xwH, rp8, csr, dinv, b0,
                                  (__half2*)hH, 1, N);
    // layer 1
    gemm_mfma<<<gG, 512, 0, stream>>>(hH, Wsw + (size_t)1 * 32768, dinv, xwH, N);
    agg_k<<<gA, 256, 0, stream>>>((const __half2*)xwH, rp8, csr, dinv, b1,
                                  (__half2*)hH, 1, N);
    // layer 2
    gemm_mfma<<<gG, 512, 0, stream>>>(hH, Wsw + (size_t)2 * 32768, dinv, xwH, N);
    agg_k<<<gA, 256, 0, stream>>>((const __half2*)xwH, rp8, csr, dinv, b2,
                                  (__half2*)hH, 0, N);

    pool_k<<<(N + 63) / 64, 128, 0, stream>>>((const __half*)hH, batch, out,
                                              pool_inv, N);
}

// Round 4
// 337.661 us; speedup vs baseline: 1.1051x; 1.0205x over previous
//
#include <hip/hip_runtime.h>
#include <hip/hip_fp16.h>

// ---------------------------------------------------------------------------
// GCNEncoder: 3x GCNConv(128->128) + ReLU(2x) + global mean pool (64 graphs)
//   - CSR build, ZERO global atomics (two-level counting sort).
//   - dinv[src] folded into GEMM epilogue (xw' = dinv*xw); csr = 4B
//     {src:u16, fp16(ew*dinv_dst)} finalized inside bucket_k.
//   - R14 result: agg MLP 4->8 gave 62->52.6us (queue-depth, not service
//     floor); dispatch-removal saved ~0 -> residual is real kernel time.
//   - R15: agg MLP -> 16 (second queue-depth data point); scat_k 512->1024
//     threads (2 blocks/CU x 16 waves = 100% occupancy, halved block lat).
// ---------------------------------------------------------------------------

#define DFEAT 128
#define BLK_E 4096   // edges per sort block
#define NPART 8

typedef _Float16 half8 __attribute__((ext_vector_type(8)));
typedef float floatx4 __attribute__((ext_vector_type(4)));

__device__ __forceinline__ int wave_incl_scan(int v) {
    int incl = v;
    #pragma unroll
    for (int off = 1; off < 64; off <<= 1) {
        int u = __shfl_up(incl, (unsigned)off, 64);
        if ((int)(threadIdx.x & 63) >= off) incl += u;
    }
    return incl;
}

__device__ __forceinline__ void wconv_elem(int idx, const float* __restrict__ W0,
                                           const float* __restrict__ W1,
                                           const float* __restrict__ W2,
                                           _Float16* __restrict__ Wsw) {
    if (idx >= 3 * 128 * 128) return;
    int w = idx >> 14;
    int r = idx & 16383;
    int k = r >> 7, nn = r & 127;
    const float* W = (w == 0) ? W0 : (w == 1) ? W1 : W2;
    float v = W[k * 128 + nn];
    _Float16 hi = (_Float16)v;
    _Float16 lo = (_Float16)((v - (float)hi) * 1024.0f);
    int kk = k >> 5, quad = (k >> 3) & 3, j = k & 7;
    int t = nn >> 4, L = quad * 16 + (nn & 15);
    int off = ((kk * 8 + t) * 64 + L) * 8 + j;
    Wsw[(size_t)(w * 2 + 0) * 16384 + off] = hi;
    Wsw[(size_t)(w * 2 + 1) * 16384 + off] = lo;
}

// K1: per-block histogram over coarse buckets (dst >> 8), bin-major output.
// Fused side work: blocks 0..47 convert/swizzle W (1024 elems each);
// blocks 0..7 zero `out` (1024 floats each).
__global__ __launch_bounds__(256) void hist_k(const int* __restrict__ dst,
                                              int* __restrict__ hist,
                                              const float* __restrict__ W0,
                                              const float* __restrict__ W1,
                                              const float* __restrict__ W2,
                                              _Float16* __restrict__ Wsw,
                                              float* __restrict__ out,
                                              int E, int nblk, int nbuck) {
    __shared__ int h[256];
    int tid = threadIdx.x, b = blockIdx.x;
    h[tid] = 0;
    // fused side work (no barrier interaction; independent outputs)
    if (b < 48) {
        #pragma unroll
        for (int k = 0; k < 4; k++)
            wconv_elem(b * 1024 + k * 256 + tid, W0, W1, W2, Wsw);
    }
    if (b < 8) {
        floatx4 z = {0.f, 0.f, 0.f, 0.f};
        ((floatx4*)out)[b * 256 + tid] = z;   // 8 blocks x 256 x 4 = 8192
    }
    __syncthreads();
    int base = b * BLK_E;
    int nE = min(BLK_E, E - base);
    for (int i = tid; i < nE; i += 256) atomicAdd(&h[dst[base + i] >> 8], 1);
    __syncthreads();
    if (tid < nbuck) hist[tid * nblk + b] = h[tid];
}

// Block-local exclusive scan, 2048 elems/block (8/thread), in-place;
// blksum = RAW per-block totals (consumers scan the <=64 of them in-LDS).
// Fused: graph end-index detection on sorted `batch` for mean-pool counts.
__global__ __launch_bounds__(256) void scanb_k(int* __restrict__ arr,
                                               int* __restrict__ blksum,
                                               const int* __restrict__ batch,
                                               int* __restrict__ gend,
                                               int n_val, int n_scan,
                                               int N, int ngraph) {
    int tid = threadIdx.x;
    int base = blockIdx.x * 2048 + tid * 8;
    int v[8], tsum = 0;
    #pragma unroll
    for (int j = 0; j < 8; j++) {
        v[j] = (base + j < n_val) ? arr[base + j] : 0;
        tsum += v[j];
    }
    int incl = wave_incl_scan(tsum);
    __shared__ int wtot[4];
    if ((tid & 63) == 63) wtot[tid >> 6] = incl;
    __syncthreads();
    int woff = 0;
    for (int w = 0; w < (tid >> 6); w++) woff += wtot[w];
    int run = woff + incl - tsum;
    #pragma unroll
    for (int j = 0; j < 8; j++) {
        if (base + j < n_scan) arr[base + j] = run;
        run += v[j];
    }
    if (tid == 255) blksum[blockIdx.x] = woff + incl;
    // fused: per-graph end indices (batch is sorted; handles empty graphs)
    int stride = gridDim.x * 256;
    for (int i = blockIdx.x * 256 + tid; i < N; i += stride) {
        int b0 = batch[i];
        int b1 = (i + 1 < N) ? batch[i + 1] : ngraph;
        if (i == 0) for (int g = 0; g < b0; g++) gend[g] = 0;
        if (b0 != b1) for (int g = b0; g < b1; g++) gend[g] = i + 1;
    }
}

// K3: scatter edges into bucket-grouped array, coalesced via LDS sort.
// rec = {src | dstlow<<16, ew_bits}. Requires N <= 65536. 1024 threads
// (R15: 2 blocks/CU x 16 waves = full occupancy; halved per-block latency).
// Fused: wave 4 scans raw blksum in-LDS; block 0 inverts pool counts.
__global__ __launch_bounds__(1024) void scat_k(const int* __restrict__ src,
                                               const int* __restrict__ dst,
                                               const float* __restrict__ ew,
                                               const int* __restrict__ offs,
                                               const int* __restrict__ blksum,
                                               const int* __restrict__ gend,
                                               float* __restrict__ pool_inv,
                                               uint2* __restrict__ rec,
                                               int E, int nblk, int nbuck,
                                               int nsb, int ngraph) {
    __shared__ int lcur[256];
    __shared__ int gbase[256];
    __shared__ uint2 srec[BLK_E];
    __shared__ int gpos[BLK_E];
    __shared__ int wtot[4];
    __shared__ int bsc[64];
    int tid = threadIdx.x, b = blockIdx.x;
    if (tid < 256) lcur[tid] = 0;
    if (tid >= 256 && tid < 320) {          // wave 4: exclusive scan of blksum
        int t = tid - 256;
        int v = (t < nsb) ? blksum[t] : 0;
        int incl = wave_incl_scan(v);
        bsc[t] = incl - v;
    }
    if (b == 0 && tid >= 320 && tid < 384) { // block 0: invert graph counts
        int t = tid - 320;
        if (t < ngraph) {
            int c = gend[t] - (t ? gend[t - 1] : 0);
            pool_inv[t] = 1.0f / fmaxf((float)c, 1.0f);
        }
    }
    __syncthreads();
    int base = b * BLK_E;
    int nE = min(BLK_E, E - base);
    for (int i = tid; i < nE; i += 1024) atomicAdd(&lcur[dst[base + i] >> 8], 1);
    __syncthreads();
    int v = 0, incl = 0;
    if (tid < 256) { v = lcur[tid]; incl = wave_incl_scan(v); }
    if (tid < 256 && (tid & 63) == 63) wtot[tid >> 6] = incl;
    __syncthreads();
    if (tid < 256) {
        int woff = 0;
        for (int w = 0; w < (tid >> 6); w++) woff += wtot[w];
        int excl = woff + incl - v;
        lcur[tid] = excl;
        int oidx = tid * nblk + b;
        gbase[tid] = (tid < nbuck) ? (offs[oidx] + bsc[oidx >> 11] - excl) : 0;
    }
    __syncthreads();
    for (int i = tid; i < nE; i += 1024) {
        int e = base + i;
        int d = dst[e];
        int bin = d >> 8;
        int slot = atomicAdd(&lcur[bin], 1);
        uint2 r;
        r.x = (unsigned)src[e] | ((unsigned)(d & 255) << 16);
        r.y = __float_as_uint(ew[e]);
        srec[slot] = r;
        gpos[slot] = gbase[bin] + slot;
    }
    __syncthreads();
    for (int i = tid; i < nE; i += 1024) rec[gpos[i]] = srec[i];
}

// K4: one block per 256-node bucket. Per-(node, src>>13) counts + fixed-point
// deg in LDS, 2048-wide scan -> rp8 segment offsets + dinv, then place FINAL
// 4B CSR entries {src:u16, fp16(ew*dinv_dst)} grouped by src partition.
__global__ __launch_bounds__(1024) void bucket_k(const uint2* __restrict__ rec,
                                                 const int* __restrict__ offs,
                                                 const int* __restrict__ blksum,
                                                 float* __restrict__ dinv,
                                                 int* __restrict__ rp8,
                                                 unsigned* __restrict__ csr,
                                                 int N, int nblk, int nsb) {
    __shared__ int cnt[2048];       // key = dl*8 + (src>>13)
    __shared__ unsigned degfx[256];
    __shared__ int cur[2048];
    __shared__ int wtot[16];
    __shared__ int bsc[64];
    int tid = threadIdx.x, bin = blockIdx.x;
    cnt[tid] = 0; cnt[tid + 1024] = 0;
    if (tid < 256) degfx[tid] = 0;
    if (tid >= 256 && tid < 320) {          // exclusive scan of raw blksum
        int t = tid - 256;
        int v = (t < nsb) ? blksum[t] : 0;
        int incl = wave_incl_scan(v);
        bsc[t] = incl - v;
    }
    __syncthreads();
    int idx0 = bin * nblk, idx1 = (bin + 1) * nblk;
    int start = offs[idx0] + bsc[idx0 >> 11];
    int endp  = offs[idx1] + bsc[idx1 >> 11];  // sentinel -> E for last bin
    for (int i = start + tid; i < endp; i += 1024) {
        uint2 r = rec[i];
        int dl = (r.x >> 16) & 255;
        int part = (r.x & 0xffff) >> 13;
        atomicAdd(&cnt[dl * NPART + part], 1);
        atomicAdd(&degfx[dl], (unsigned)(__uint_as_float(r.y) * 1048576.0f + 0.5f));
    }
    __syncthreads();
    int v0 = cnt[tid * 2], v1 = cnt[tid * 2 + 1];
    int tsum = v0 + v1;
    int incl = wave_incl_scan(tsum);
    if ((tid & 63) == 63) wtot[tid >> 6] = incl;
    __syncthreads();
    int woff = 0;
    for (int w = 0; w < (tid >> 6); w++) woff += wtot[w];
    int texcl = woff + incl - tsum;
    cur[tid * 2] = texcl;
    cur[tid * 2 + 1] = texcl + v0;
    // nodes >= N in the tail bucket have zero counts -> their rp8 slots get
    // the bucket end offset, which serves as the sentinel for node N-1.
    rp8[bin * 2048 + tid * 2] = start + texcl;
    rp8[bin * 2048 + tid * 2 + 1] = start + texcl + v0;
    __syncthreads();
    if (tid < 256) {
        int node = bin * 256 + tid;
        if (node < N) {
            float deg = (float)degfx[tid] * (1.0f / 1048576.0f) + 1.0f;
            float di = rsqrtf(deg);
            dinv[node] = di;
            degfx[tid] = __float_as_uint(di);   // stash dinv
        }
    }
    __syncthreads();
    for (int i = start + tid; i < endp; i += 1024) {
        uint2 r = rec[i];
        int dl = (r.x >> 16) & 255;
        int s = r.x & 0xffff;
        int part = s >> 13;
        int p = start + atomicAdd(&cur[dl * NPART + part], 1);
        float di_d = __uint_as_float(degfx[dl]);
        float nm = __uint_as_float(r.y) * di_d;   // ew * dinv_dst (final)
        unsigned h = (unsigned)__half_as_ushort(__float2half_rn(nm));
        csr[p] = (unsigned)s | (h << 16);
    }
}

// MFMA GEMM core (A fp16). Epilogue scales row by dinv[row]:
// C[i] = dinv[i] * (A[i] @ W). Block: 8 waves, 128 rows.
__global__ __launch_bounds__(512) void gemm_mfma(const _Float16* __restrict__ A,
                                                 const _Float16* __restrict__ Wsw,
                                                 const float* __restrict__ dinv,
                                                 _Float16* __restrict__ C, int n) {
    __shared__ _Float16 Bl[2 * 16384];
    {
        const uint4* s = (const uint4*)Wsw;
        uint4* d = (uint4*)Bl;
        for (int i = threadIdx.x; i < 4096; i += 512) d[i] = s[i];
    }
    int wave = threadIdx.x >> 6, lane = threadIdx.x & 63;
    int quad = lane >> 4, mcol = lane & 15;
    int row0 = blockIdx.x * 128 + wave * 16 + mcol;
    half8 af[4] = {};
    if (row0 < n) {
        const half8* Arow = (const half8*)(A + (size_t)row0 * DFEAT);
        af[0] = Arow[0 + quad];
        af[1] = Arow[4 + quad];
        af[2] = Arow[8 + quad];
        af[3] = Arow[12 + quad];
    }
    __syncthreads();
    floatx4 acch[8] = {};
    floatx4 accl[8] = {};
    const half8* Bh = (const half8*)Bl;
    const half8* Blo = (const half8*)(Bl + 16384);
    #pragma unroll
    for (int kk = 0; kk < 4; kk++) {
        #pragma unroll
        for (int t = 0; t < 8; t++) {
            half8 bh = Bh[(kk * 8 + t) * 64 + lane];
            acch[t] = __builtin_amdgcn_mfma_f32_16x16x32_f16(af[kk], bh, acch[t], 0, 0, 0);
            half8 bl = Blo[(kk * 8 + t) * 64 + lane];
            accl[t] = __builtin_amdgcn_mfma_f32_16x16x32_f16(af[kk], bl, accl[t], 0, 0, 0);
        }
    }
    int orow_base = blockIdx.x * 128 + wave * 16 + quad * 4;
    float dv[4];
    #pragma unroll
    for (int r = 0; r < 4; r++)
        dv[r] = (orow_base + r < n) ? dinv[orow_base + r] : 0.f;
    #pragma unroll
    for (int t = 0; t < 8; t++) {
        #pragma unroll
        for (int r = 0; r < 4; r++) {
            int orow = orow_base + r;
            if (orow < n) {
                float v = (acch[t][r] + accl[t][r] * (1.0f / 1024.0f)) * dv[r];
                C[(size_t)orow * DFEAT + t * 16 + mcol] = (_Float16)v;
            }
        }
    }
}

// Same, but reads fp32 A (layer 0: x directly).
__global__ __launch_bounds__(512) void gemm_mfma_f32(const float* __restrict__ A,
                                                     const _Float16* __restrict__ Wsw,
                                                     const float* __restrict__ dinv,
                                                     _Float16* __restrict__ C, int n) {
    __shared__ _Float16 Bl[2 * 16384];
    {
        const uint4* s = (const uint4*)Wsw;
        uint4* d = (uint4*)Bl;
        for (int i = threadIdx.x; i < 4096; i += 512) d[i] = s[i];
    }
    int wave = threadIdx.x >> 6, lane = threadIdx.x & 63;
    int quad = lane >> 4, mcol = lane & 15;
    int row0 = blockIdx.x * 128 + wave * 16 + mcol;
    half8 af[4] = {};
    if (row0 < n) {
        const float4* Arow = (const float4*)(A + (size_t)row0 * DFEAT);
        #pragma unroll
        for (int kk = 0; kk < 4; kk++) {
            float4 f0 = Arow[kk * 8 + quad * 2];
            float4 f1 = Arow[kk * 8 + quad * 2 + 1];
            half8 a;
            a[0] = (_Float16)f0.x; a[1] = (_Float16)f0.y;
            a[2] = (_Float16)f0.z; a[3] = (_Float16)f0.w;
            a[4] = (_Float16)f1.x; a[5] = (_Float16)f1.y;
            a[6] = (_Float16)f1.z; a[7] = (_Float16)f1.w;
            af[kk] = a;
        }
    }
    __syncthreads();
    floatx4 acch[8] = {};
    floatx4 accl[8] = {};
    const half8* Bh = (const half8*)Bl;
    const half8* Blo = (const half8*)(Bl + 16384);
    #pragma unroll
    for (int kk = 0; kk < 4; kk++) {
        #pragma unroll
        for (int t = 0; t < 8; t++) {
            half8 bh = Bh[(kk * 8 + t) * 64 + lane];
            acch[t] = __builtin_amdgcn_mfma_f32_16x16x32_f16(af[kk], bh, acch[t], 0, 0, 0);
            half8 bl = Blo[(kk * 8 + t) * 64 + lane];
            accl[t] = __builtin_amdgcn_mfma_f32_16x16x32_f16(af[kk], bl, accl[t], 0, 0, 0);
        }
    }
    int orow_base = blockIdx.x * 128 + wave * 16 + quad * 4;
    float dv[4];
    #pragma unroll
    for (int r = 0; r < 4; r++)
        dv[r] = (orow_base + r < n) ? dinv[orow_base + r] : 0.f;
    #pragma unroll
    for (int t = 0; t < 8; t++) {
        #pragma unroll
        for (int r = 0; r < 4; r++) {
            int orow = orow_base + r;
            if (orow < n) {
                float v = (acch[t][r] + accl[t][r] * (1.0f / 1024.0f)) * dv[r];
                C[(size_t)orow * DFEAT + t * 16 + mcol] = (_Float16)v;
            }
        }
    }
}

// 4 nodes per 256-thread block (one wave each); lane holds 2 fp16 features.
// R15: 16-deep gather unroll (second MLP data point; VGPR ~60).
__global__ __launch_bounds__(256) void agg_k(const __half2* __restrict__ xw2,
                                             const int* __restrict__ rp8,
                                             const unsigned* __restrict__ csr,
                                             const float* __restrict__ dinv,
                                             const float* __restrict__ bias,
                                             __half2* __restrict__ out, int relu, int n) {
    int node = blockIdx.x * 4 + (threadIdx.x >> 6);
    if (node >= n) return;
    int lane = threadIdx.x & 63;
    float di = dinv[node];
    float2 selfv = __half22float2(xw2[(size_t)node * 64 + lane]);
    float ax = di * selfv.x, ay = di * selfv.y;
    int e = rp8[node * NPART], end = rp8[node * NPART + NPART];
    for (; e + 16 <= end; e += 16) {
        unsigned c[16];
        #pragma unroll
        for (int j = 0; j < 16; j++) c[j] = csr[e + j];
        float2 v[16];
        #pragma unroll
        for (int j = 0; j < 16; j++)
            v[j] = __half22float2(xw2[(size_t)(c[j] & 0xffff) * 64 + lane]);
        #pragma unroll
        for (int j = 0; j < 16; j++) {
            float w = __half2float(__ushort_as_half((unsigned short)(c[j] >> 16)));
            ax = fmaf(w, v[j].x, ax); ay = fmaf(w, v[j].y, ay);
        }
    }
    for (; e + 8 <= end; e += 8) {
        unsigned c[8];
        #pragma unroll
        for (int j = 0; j < 8; j++) c[j] = csr[e + j];
        float2 v[8];
        #pragma unroll
        for (int j = 0; j < 8; j++)
            v[j] = __half22float2(xw2[(size_t)(c[j] & 0xffff) * 64 + lane]);
        #pragma unroll
        for (int j = 0; j < 8; j++) {
            float w = __half2float(__ushort_as_half((unsigned short)(c[j] >> 16)));
            ax = fmaf(w, v[j].x, ax); ay = fmaf(w, v[j].y, ay);
        }
    }
    for (; e + 4 <= end; e += 4) {
        unsigned c0 = csr[e + 0], c1 = csr[e + 1];
        unsigned c2 = csr[e + 2], c3 = csr[e + 3];
        float2 v0 = __half22float2(xw2[(size_t)(c0 & 0xffff) * 64 + lane]);
        float2 v1 = __half22float2(xw2[(size_t)(c1 & 0xffff) * 64 + lane]);
        float2 v2 = __half22float2(xw2[(size_t)(c2 & 0xffff) * 64 + lane]);
        float2 v3 = __half22float2(xw2[(size_t)(c3 & 0xffff) * 64 + lane]);
        float w0 = __half2float(__ushort_as_half((unsigned short)(c0 >> 16)));
        float w1 = __half2float(__ushort_as_half((unsigned short)(c1 >> 16)));
        float w2 = __half2float(__ushort_as_half((unsigned short)(c2 >> 16)));
        float w3 = __half2float(__ushort_as_half((unsigned short)(c3 >> 16)));
        ax = fmaf(w0, v0.x, ax); ay = fmaf(w0, v0.y, ay);
        ax = fmaf(w1, v1.x, ax); ay = fmaf(w1, v1.y, ay);
        ax = fmaf(w2, v2.x, ax); ay = fmaf(w2, v2.y, ay);
        ax = fmaf(w3, v3.x, ax); ay = fmaf(w3, v3.y, ay);
    }
    for (; e < end; e++) {
        unsigned c = csr[e];
        float w = __half2float(__ushort_as_half((unsigned short)(c >> 16)));
        float2 v = __half22float2(xw2[(size_t)(c & 0xffff) * 64 + lane]);
        ax = fmaf(w, v.x, ax); ay = fmaf(w, v.y, ay);
    }
    float2 bv = ((const float2*)bias)[lane];
    ax += bv.x; ay += bv.y;
    if (relu) { ax = fmaxf(ax, 0.f); ay = fmaxf(ay, 0.f); }
    out[(size_t)node * 64 + lane] = __floats2half2_rn(ax, ay);
}

// batch is sorted: chunk of 64 nodes per block, 128 threads (one per feature).
// Contributions pre-scaled by 1/cnt (pool_inv) -> no div_k pass.
__global__ __launch_bounds__(128) void pool_k(const __half* __restrict__ h,
                                              const int* __restrict__ batch,
                                              float* __restrict__ out,
                                              const float* __restrict__ pool_inv, int n) {
    int j = threadIdx.x;
    int start = blockIdx.x * 64;
    if (start >= n) return;
    int end = start + 64; if (end > n) end = n;
    int g = batch[start];
    float acc = 0.f;
    for (int i = start; i < end; i++) {
        int bi = batch[i];
        if (bi != g) {
            atomicAdd(&out[g * DFEAT + j], acc * pool_inv[g]);
            acc = 0.f; g = bi;
        }
        acc += __half2float(h[(size_t)i * DFEAT + j]);
    }
    atomicAdd(&out[g * DFEAT + j], acc * pool_inv[g]);
}

extern "C" void kernel_launch(void* const* d_in, const int* in_sizes, int n_in,
                              void* d_out, int out_size, void* d_ws, size_t ws_size,
                              hipStream_t stream) {
    const float* x    = (const float*)d_in[0];
    const int*  eidx  = (const int*)d_in[1];
    const float* ew   = (const float*)d_in[2];
    const int*  batch = (const int*)d_in[3];
    const float* W0 = (const float*)d_in[4];
    const float* b0 = (const float*)d_in[5];
    const float* W1 = (const float*)d_in[6];
    const float* b1 = (const float*)d_in[7];
    const float* W2 = (const float*)d_in[8];
    const float* b2 = (const float*)d_in[9];
    float* out = (float*)d_out;

    const int N = in_sizes[0] / DFEAT;   // 50000 (must be <= 65536)
    const int E = in_sizes[2];           // 1600000
    const int ngraph = out_size / DFEAT; // 64 (sizes are in ELEMENTS)
    const int* src = eidx;
    const int* dst = eidx + E;

    const int nbuck = (N + 255) / 256;           // 196
    const int nblk  = (E + BLK_E - 1) / BLK_E;   // 391
    const int total = nbuck * nblk;
    const int n_scan = total + 1;                // sentinel -> E
    const int nsb = (n_scan + 2047) / 2048;      // 38 (must be <= 64)

    size_t off = 0;
    auto walloc = [&](size_t bytes) -> void* {
        void* p = (char*)d_ws + off;
        off += (bytes + 255) & ~(size_t)255;
        return p;
    };
    float*   dinv    = (float*)  walloc((size_t)N * 4);
    int*     rp8     = (int*)    walloc(((size_t)nbuck * 2048 + 8) * 4);
    int*     offs    = (int*)    walloc((size_t)n_scan * 4);
    int*     blksum  = (int*)    walloc(256 * 4);
    uint2*   rec     = (uint2*)  walloc((size_t)E * 8);
    unsigned* csr    = (unsigned*)walloc((size_t)E * 4);
    _Float16* xwH    = (_Float16*)walloc((size_t)N * DFEAT * 2);
    _Float16* hH     = (_Float16*)walloc((size_t)N * DFEAT * 2);
    _Float16* Wsw    = (_Float16*)walloc((size_t)6 * 16384 * 2);
    float*   pool_inv= (float*)  walloc(64 * 4);
    int*     gend    = (int*)    walloc(64 * 4);

    // ---- CSR build (no global atomics); hist fused with wconv + zeroing ----
    hist_k<<<nblk, 256, 0, stream>>>(dst, offs, W0, W1, W2, Wsw, out,
                                     E, nblk, nbuck);
    scanb_k<<<nsb, 256, 0, stream>>>(offs, blksum, batch, gend, total, n_scan,
                                     N, ngraph);
    scat_k<<<nblk, 1024, 0, stream>>>(src, dst, ew, offs, blksum, gend, pool_inv,
                                      rec, E, nblk, nbuck, nsb, ngraph);
    bucket_k<<<nbuck, 1024, 0, stream>>>(rec, offs, blksum, dinv, rp8, csr,
                                         N, nblk, nsb);

    int gG = (N + 127) / 128;
    int gA = (N + 3) / 4;
    // layer 0 (reads fp32 x directly)
    gemm_mfma_f32<<<gG, 512, 0, stream>>>(x, Wsw + (size_t)0 * 32768, dinv, xwH, N);
    agg_k<<<gA, 256, 0, stream>>>((const __half2*)xwH, rp8, csr, dinv, b0,
                                  (__half2*)hH, 1, N);
    // layer 1
    gemm_mfma<<<gG, 512, 0, stream>>>(hH, Wsw + (size_t)1 * 32768, dinv, xwH, N);
    agg_k<<<gA, 256, 0, stream>>>((const __half2*)xwH, rp8, csr, dinv, b1,
                                  (__half2*)hH, 1, N);
    // layer 2
    gemm_mfma<<<gG, 512, 0, stream>>>(hH, Wsw + (size_t)2 * 32768, dinv, xwH, N);
    agg_k<<<gA, 256, 0, stream>>>((const __half2*)xwH, rp8, csr, dinv, b2,
                                  (__half2*)hH, 0, N);

    pool_k<<<(N + 63) / 64, 128, 0, stream>>>((const __half*)hH, batch, out,
                                              pool_inv, N);
}